// Round 5
// baseline (577.246 us; speedup 1.0000x reference)
//
#include <hip/hip_runtime.h>
#include <hip/hip_bf16.h>

#define NN 100000
#define NE 1600000
#define NG 1000
#define SMAX 48

typedef unsigned short u16;
typedef unsigned int u32;
typedef u16 u16x8 __attribute__((ext_vector_type(8)));
typedef u32 u32x4 __attribute__((ext_vector_type(4)));
typedef float f32x4 __attribute__((ext_vector_type(4)));
typedef __attribute__((ext_vector_type(8))) short s16x8;
typedef __attribute__((ext_vector_type(4))) float facc4;

__device__ __forceinline__ float bf2f(u16 u) {
    union { u32 i; float f; } c; c.i = ((u32)u) << 16; return c.f;
}
__device__ __forceinline__ u16 f2bf(float f) {
    __hip_bfloat16 h = __float2bfloat16(f);
    union { __hip_bfloat16 h; u16 u; } c; c.h = h; return c.u;
}
__device__ __forceinline__ int ntload(const int* p) { return __builtin_nontemporal_load(p); }

// ---------------- dtype detector: flag=1 if x is bf16, 0 if f32 ----------------
__global__ __launch_bounds__(256) void detect_kernel(const u32* __restrict__ xr, int* __restrict__ flag) {
    __shared__ int cnt[256];
    int c = 0;
    for (int i = threadIdx.x; i < 4096; i += 256) {
        u32 e = (xr[i] >> 7) & 0xFFu;
        if (e >= 110u && e <= 135u) c++;
    }
    cnt[threadIdx.x] = c;
    __syncthreads();
    for (int o = 128; o > 0; o >>= 1) {
        if (threadIdx.x < o) cnt[threadIdx.x] += cnt[threadIdx.x + o];
        __syncthreads();
    }
    if (threadIdx.x == 0) flag[0] = (cnt[0] > 2048) ? 1 : 0;
}

// ---------------- MEGA prep: cvt_x | cvt_wt x4 | cvt_b x4 | hist(1/thr), by block range -------
// ranges: [0,6250) cvt_x ; [6250,6474) cvt_wt ; [6474,6476) cvt_b ; [6476,12726) hist
#define MEGA_NB 12726
__global__ __launch_bounds__(256) void mega_prep(
    const void* __restrict__ x, const int* __restrict__ flag, u16* __restrict__ xb,
    const void* __restrict__ Wemb, const void* __restrict__ W1, const void* __restrict__ W2,
    const void* __restrict__ W3, u16* __restrict__ wembT, u16* __restrict__ w1T,
    u16* __restrict__ w2T, u16* __restrict__ w3T,
    const void* __restrict__ bemb, const void* __restrict__ b1, const void* __restrict__ b2,
    const void* __restrict__ b3, float* __restrict__ bembF, float* __restrict__ b1F,
    float* __restrict__ b2F, float* __restrict__ b3F,
    const int* __restrict__ ei, int* __restrict__ counts)
{
    int b = blockIdx.x, tid = threadIdx.x;
    int fl = flag[0];
    if (b < 6250) {                       // ---- cvt_x (skip when already bf16)
        if (fl) return;
        int c = b * 256 + tid;
        f32x4 a = reinterpret_cast<const f32x4*>(x)[c * 2];
        f32x4 d = reinterpret_cast<const f32x4*>(x)[c * 2 + 1];
        u16x8 o;
        #pragma unroll
        for (int j = 0; j < 4; ++j) { o[j] = f2bf(a[j]); o[4 + j] = f2bf(d[j]); }
        reinterpret_cast<u16x8*>(xb)[c] = o;
    } else if (b < 6474) {                // ---- cvt_wt (transpose W[k][m] -> Wt[m][k])
        int o = (b - 6250) * 256 + tid;
        const void* src; u16* dst; int M; int ol;
        if (o < 16384)      { src = Wemb; dst = wembT; M = 128; ol = o; }
        else if (o < 32768) { src = W1;   dst = w1T;   M = 128; ol = o - 16384; }
        else if (o < 49152) { src = W2;   dst = w2T;   M = 128; ol = o - 32768; }
        else                { src = W3;   dst = w3T;   M = 64;  ol = o - 49152; }
        int n = ol >> 7, k = ol & 127;
        u16 v = fl ? reinterpret_cast<const u16*>(src)[k * M + n]
                   : f2bf(reinterpret_cast<const float*>(src)[k * M + n]);
        dst[ol] = v;
    } else if (b < 6476) {                // ---- cvt_b
        int i = (b - 6474) * 256 + tid;
        if (i >= 448) return;
        const void* src; float* dst; int il;
        if (i < 128)      { src = bemb; dst = bembF; il = i; }
        else if (i < 256) { src = b1;   dst = b1F;   il = i - 128; }
        else if (i < 384) { src = b2;   dst = b2F;   il = i - 256; }
        else              { src = b3;   dst = b3F;   il = i - 384; }
        dst[il] = fl ? bf2f(reinterpret_cast<const u16*>(src)[il])
                     : reinterpret_cast<const float*>(src)[il];
    } else {                              // ---- hist (1 edge / thread: max TLP)
        int e = (b - 6476) * 256 + tid;
        if (e < NE) atomicAdd(&counts[ei[NE + e]], 1);
    }
}

// ---------------- scan1 (+ dis, + cursor zero) ----------------
__global__ __launch_bounds__(256) void scan1_kernel(const int* __restrict__ counts, int* __restrict__ offs,
                                                    int* __restrict__ bsums, float* __restrict__ dis,
                                                    int* __restrict__ cursor) {
    __shared__ int sums[256];
    int tid = threadIdx.x;
    int base = blockIdx.x * 2048 + tid * 8;
    int local[8];
    int s = 0;
    #pragma unroll
    for (int i = 0; i < 8; ++i) {
        int v = 0;
        if (base + i < NN) {
            v = counts[base + i];
            dis[base + i] = rsqrtf((float)v + 1.0f);
            cursor[base + i] = 0;
        }
        local[i] = s; s += v;
    }
    sums[tid] = s;
    __syncthreads();
    for (int o = 1; o < 256; o <<= 1) {
        int v = (tid >= o) ? sums[tid - o] : 0;
        __syncthreads();
        sums[tid] += v;
        __syncthreads();
    }
    int excl = sums[tid] - s;
    #pragma unroll
    for (int i = 0; i < 8; ++i)
        if (base + i < NN) offs[base + i] = excl + local[i];
    if (tid == 255) bsums[blockIdx.x] = sums[255];
}

// ---------------- scan3 (folds block-sum prefix) ----------------
__global__ __launch_bounds__(256) void scan3_kernel(int* __restrict__ offs, const int* __restrict__ bsums) {
    __shared__ int addv;
    int i = blockIdx.x * 256 + threadIdx.x;
    int bucket = blockIdx.x >> 3;
    if (threadIdx.x == 0) {
        int s = 0;
        for (int k = 0; k < bucket; ++k) s += bsums[k];
        addv = s;
    }
    __syncthreads();
    if (i < NN) offs[i] += addv;
}

// ---------------- MEGA2: gemm_emb [0,1563) | scatter 1-edge/thr [1563,7813) ----------------
__global__ __launch_bounds__(256) void mega2_kernel(
    const u16* __restrict__ Hin, const u16* __restrict__ HinAlt, const int* __restrict__ flag,
    const u16* __restrict__ Wt, const float* __restrict__ bias, u16* __restrict__ Hout,
    const int* __restrict__ ei, const int* __restrict__ offs, int* __restrict__ cursor,
    int* __restrict__ srcs)
{
    __shared__ u16 sW[128 * 136];
    int b = blockIdx.x, tid = threadIdx.x;
    if (b < 1563) {
        // ---- gemm_emb: 64 rows/block, Hout = A @ W_emb + b_emb
        const u16* A = flag[0] ? HinAlt : Hin;
        for (int c = tid; c < 128 * 16; c += 256) {
            int n = c >> 4, kc = (c & 15) << 3;
            *reinterpret_cast<u16x8*>(sW + n * 136 + kc) = reinterpret_cast<const u16x8*>(Wt)[c];
        }
        __syncthreads();
        int wv = tid >> 6, lane = tid & 63;
        int m = lane & 15, quad = lane >> 4;
        int r0 = b * 64 + wv * 16;
        int ar = r0 + m; if (ar >= NN) ar = NN - 1;
        facc4 acc[8];
        #pragma unroll
        for (int t = 0; t < 8; ++t) acc[t] = (facc4){0.f, 0.f, 0.f, 0.f};
        const u16* arow = A + (size_t)ar * 128 + quad * 8;
        #pragma unroll
        for (int k0 = 0; k0 < 128; k0 += 32) {
            s16x8 a = *reinterpret_cast<const s16x8*>(arow + k0);
            #pragma unroll
            for (int t = 0; t < 8; ++t) {
                s16x8 bfr = *reinterpret_cast<const s16x8*>(sW + (t * 16 + m) * 136 + k0 + quad * 8);
                acc[t] = __builtin_amdgcn_mfma_f32_16x16x32_bf16(a, bfr, acc[t], 0, 0, 0);
            }
        }
        #pragma unroll
        for (int t = 0; t < 8; ++t) {
            int col = t * 16 + m;
            float bv = bias[col];
            #pragma unroll
            for (int r = 0; r < 4; ++r) {
                int orow = r0 + quad * 4 + r;
                if (orow < NN)
                    Hout[(size_t)orow * 128 + col] = f2bf(acc[t][r] + bv);
            }
        }
    } else {
        // ---- scatter: 1 edge/thread
        int e = (b - 1563) * 256 + tid;
        if (e < NE) {
            int s = ei[e], d = ei[NE + e];
            int pos = offs[d] + atomicAdd(&cursor[d], 1);
            srcs[pos] = s;
        }
    }
}

// ---------------- MFMA GEMM (layer-1): Hout[N,128] = Hin @ W1 ----------------
__global__ __launch_bounds__(256) void gemm_mfma128(const u16* __restrict__ Hin, const u16* __restrict__ Wt,
                                                    u16* __restrict__ Hout) {
    __shared__ u16 sW[128 * 136];
    int tid = threadIdx.x;
    for (int c = tid; c < 128 * 16; c += 256) {
        int n = c >> 4, kc = (c & 15) << 3;
        *reinterpret_cast<u16x8*>(sW + n * 136 + kc) = reinterpret_cast<const u16x8*>(Wt)[c];
    }
    __syncthreads();
    int wv = tid >> 6, lane = tid & 63;
    int m = lane & 15, quad = lane >> 4;
    int r0 = blockIdx.x * 64 + wv * 16;
    int ar = r0 + m; if (ar >= NN) ar = NN - 1;
    facc4 acc[8];
    #pragma unroll
    for (int t = 0; t < 8; ++t) acc[t] = (facc4){0.f, 0.f, 0.f, 0.f};
    const u16* arow = Hin + (size_t)ar * 128 + quad * 8;
    #pragma unroll
    for (int k0 = 0; k0 < 128; k0 += 32) {
        s16x8 a = *reinterpret_cast<const s16x8*>(arow + k0);
        #pragma unroll
        for (int t = 0; t < 8; ++t) {
            s16x8 bfr = *reinterpret_cast<const s16x8*>(sW + (t * 16 + m) * 136 + k0 + quad * 8);
            acc[t] = __builtin_amdgcn_mfma_f32_16x16x32_bf16(a, bfr, acc[t], 0, 0, 0);
        }
    }
    #pragma unroll
    for (int t = 0; t < 8; ++t) {
        int col = t * 16 + m;
        #pragma unroll
        for (int r = 0; r < 4; ++r) {
            int orow = r0 + quad * 4 + r;
            if (orow < NN)
                Hout[(size_t)orow * 128 + col] = f2bf(acc[t][r]);
        }
    }
}

// ---------------- FUSED: agg(128-wide, +bias, relu) -> LDS -> MFMA gemm (x W[128,MOUT]) -------
template <int MOUT>
__global__ __launch_bounds__(256) void fused_agg_gemm(const u16* __restrict__ T, const int* __restrict__ offs,
                                                      const int* __restrict__ counts, const float* __restrict__ dis,
                                                      const int* __restrict__ srcs, const float* __restrict__ aggbias,
                                                      const u16* __restrict__ Wt, u16* __restrict__ Hout) {
    constexpr int LDW = 136;
    __shared__ u16 sW[MOUT * LDW];
    __shared__ u16 sA[64 * LDW];
    int tid = threadIdx.x;
    for (int c = tid; c < MOUT * 16; c += 256) {
        int n = c >> 4, kc = (c & 15) << 3;
        *reinterpret_cast<u16x8*>(sW + n * LDW + kc) = reinterpret_cast<const u16x8*>(Wt)[c];
    }

    int lane = tid & 15, grp = tid >> 4;
    const u32x4* T4 = reinterpret_cast<const u32x4*>(T);
    for (int i = 0; i < 4; ++i) {
        int nl = grp * 4 + i;
        int n = blockIdx.x * 64 + nl;
        bool valid = n < NN;
        int nc = valid ? n : NN - 1;
        float di = dis[nc];
        float sn = di * di;
        u32x4 ts = T4[(size_t)nc * 16 + lane];
        float acc[8];
        #pragma unroll
        for (int q = 0; q < 4; ++q) {
            acc[2 * q]     = bf2f((u16)(ts[q] & 0xffffu)) * sn + aggbias[lane * 8 + 2 * q];
            acc[2 * q + 1] = bf2f((u16)(ts[q] >> 16))     * sn + aggbias[lane * 8 + 2 * q + 1];
        }
        int st = offs[nc], cnt = valid ? counts[nc] : 0;
        int j = 0;
        for (; j + 4 <= cnt; j += 4) {
            int e0 = ntload(srcs + st + j);
            int e1 = ntload(srcs + st + j + 1);
            int e2 = ntload(srcs + st + j + 2);
            int e3 = ntload(srcs + st + j + 3);
            float w0 = dis[e0] * di, w1 = dis[e1] * di, w2 = dis[e2] * di, w3 = dis[e3] * di;
            u32x4 g0 = T4[(size_t)e0 * 16 + lane];
            u32x4 g1 = T4[(size_t)e1 * 16 + lane];
            u32x4 g2 = T4[(size_t)e2 * 16 + lane];
            u32x4 g3 = T4[(size_t)e3 * 16 + lane];
            #pragma unroll
            for (int q = 0; q < 4; ++q) {
                acc[2 * q]     += bf2f((u16)(g0[q] & 0xffffu)) * w0;
                acc[2 * q + 1] += bf2f((u16)(g0[q] >> 16))     * w0;
                acc[2 * q]     += bf2f((u16)(g1[q] & 0xffffu)) * w1;
                acc[2 * q + 1] += bf2f((u16)(g1[q] >> 16))     * w1;
                acc[2 * q]     += bf2f((u16)(g2[q] & 0xffffu)) * w2;
                acc[2 * q + 1] += bf2f((u16)(g2[q] >> 16))     * w2;
                acc[2 * q]     += bf2f((u16)(g3[q] & 0xffffu)) * w3;
                acc[2 * q + 1] += bf2f((u16)(g3[q] >> 16))     * w3;
            }
        }
        for (; j < cnt; ++j) {
            int e = ntload(srcs + st + j);
            float w = dis[e] * di;
            u32x4 g = T4[(size_t)e * 16 + lane];
            #pragma unroll
            for (int q = 0; q < 4; ++q) {
                acc[2 * q]     += bf2f((u16)(g[q] & 0xffffu)) * w;
                acc[2 * q + 1] += bf2f((u16)(g[q] >> 16))     * w;
            }
        }
        u16x8 pk;
        #pragma unroll
        for (int q = 0; q < 4; ++q) {
            pk[2 * q]     = f2bf(fmaxf(acc[2 * q], 0.0f));
            pk[2 * q + 1] = f2bf(fmaxf(acc[2 * q + 1], 0.0f));
        }
        *reinterpret_cast<u16x8*>(sA + nl * LDW + lane * 8) = pk;
    }
    __syncthreads();

    int wv = tid >> 6, l64 = tid & 63;
    int m = l64 & 15, quad = l64 >> 4;
    int r0 = blockIdx.x * 64 + wv * 16;
    constexpr int NT = MOUT / 16;
    facc4 gacc[NT];
    #pragma unroll
    for (int t = 0; t < NT; ++t) gacc[t] = (facc4){0.f, 0.f, 0.f, 0.f};
    #pragma unroll
    for (int k0 = 0; k0 < 128; k0 += 32) {
        s16x8 a = *reinterpret_cast<const s16x8*>(sA + (wv * 16 + m) * LDW + k0 + quad * 8);
        #pragma unroll
        for (int t = 0; t < NT; ++t) {
            s16x8 bfr = *reinterpret_cast<const s16x8*>(sW + (t * 16 + m) * LDW + k0 + quad * 8);
            gacc[t] = __builtin_amdgcn_mfma_f32_16x16x32_bf16(a, bfr, gacc[t], 0, 0, 0);
        }
    }
    #pragma unroll
    for (int t = 0; t < NT; ++t) {
        int col = t * 16 + m;
        #pragma unroll
        for (int r = 0; r < 4; ++r) {
            int orow = r0 + quad * 4 + r;
            if (orow < NN)
                Hout[(size_t)orow * MOUT + col] = f2bf(gacc[t][r]);
        }
    }
}

// ---------------- FUSED agg3 (+b3, no relu) + global add pool -> f32 outF ----------------
// 32 nodes/block (NN % 32 == 0), 8 lanes/node x 8 feats. batch sorted -> per-block
// graph span tiny; LDS accumulate then atomic flush.
__global__ __launch_bounds__(256) void agg_pool_kernel(const u16* __restrict__ T, const int* __restrict__ offs,
                                                       const int* __restrict__ counts, const float* __restrict__ dis,
                                                       const int* __restrict__ srcs, const float* __restrict__ bias,
                                                       const int* __restrict__ batch, float* __restrict__ outF) {
    __shared__ float accG[SMAX * 64];
    __shared__ int sg0;
    int tid = threadIdx.x;
    for (int i = tid; i < SMAX * 64; i += 256) accG[i] = 0.0f;
    if (tid == 0) sg0 = batch[blockIdx.x * 32];
    __syncthreads();
    int g0 = sg0;
    int lane = tid & 7;
    int n = blockIdx.x * 32 + (tid >> 3);

    const u32x4* T4 = reinterpret_cast<const u32x4*>(T);
    float di = dis[n];
    float sn = di * di;
    u32x4 ts = T4[(size_t)n * 8 + lane];
    float acc[8];
    #pragma unroll
    for (int q = 0; q < 4; ++q) {
        acc[2 * q]     = bf2f((u16)(ts[q] & 0xffffu)) * sn + bias[lane * 8 + 2 * q];
        acc[2 * q + 1] = bf2f((u16)(ts[q] >> 16))     * sn + bias[lane * 8 + 2 * q + 1];
    }
    int st = offs[n], cnt = counts[n];
    int j = 0;
    for (; j + 4 <= cnt; j += 4) {
        int e0 = ntload(srcs + st + j);
        int e1 = ntload(srcs + st + j + 1);
        int e2 = ntload(srcs + st + j + 2);
        int e3 = ntload(srcs + st + j + 3);
        float w0 = dis[e0] * di, w1 = dis[e1] * di, w2 = dis[e2] * di, w3 = dis[e3] * di;
        u32x4 g0v = T4[(size_t)e0 * 8 + lane];
        u32x4 g1v = T4[(size_t)e1 * 8 + lane];
        u32x4 g2v = T4[(size_t)e2 * 8 + lane];
        u32x4 g3v = T4[(size_t)e3 * 8 + lane];
        #pragma unroll
        for (int q = 0; q < 4; ++q) {
            acc[2 * q]     += bf2f((u16)(g0v[q] & 0xffffu)) * w0;
            acc[2 * q + 1] += bf2f((u16)(g0v[q] >> 16))     * w0;
            acc[2 * q]     += bf2f((u16)(g1v[q] & 0xffffu)) * w1;
            acc[2 * q + 1] += bf2f((u16)(g1v[q] >> 16))     * w1;
            acc[2 * q]     += bf2f((u16)(g2v[q] & 0xffffu)) * w2;
            acc[2 * q + 1] += bf2f((u16)(g2v[q] >> 16))     * w2;
            acc[2 * q]     += bf2f((u16)(g3v[q] & 0xffffu)) * w3;
            acc[2 * q + 1] += bf2f((u16)(g3v[q] >> 16))     * w3;
        }
    }
    for (; j < cnt; ++j) {
        int e = ntload(srcs + st + j);
        float w = dis[e] * di;
        u32x4 g = T4[(size_t)e * 8 + lane];
        #pragma unroll
        for (int q = 0; q < 4; ++q) {
            acc[2 * q]     += bf2f((u16)(g[q] & 0xffffu)) * w;
            acc[2 * q + 1] += bf2f((u16)(g[q] >> 16))     * w;
        }
    }

    int s = batch[n] - g0;
    if (s >= 0 && s < SMAX) {
        #pragma unroll
        for (int q = 0; q < 8; ++q)
            atomicAdd(&accG[s * 64 + lane * 8 + q], acc[q]);
    } else {
        #pragma unroll
        for (int q = 0; q < 8; ++q)
            atomicAdd(&outF[(size_t)(g0 + s) * 64 + lane * 8 + q], acc[q]);
    }
    __syncthreads();
    int gend = batch[blockIdx.x * 32 + 31];
    int span = gend - g0 + 1;
    if (span > SMAX) span = SMAX;
    for (int i = tid; i < span * 64; i += 256)
        atomicAdd(&outF[(size_t)g0 * 64 + i], accG[i]);
}

// ---------------- outF -> d_out (dtype branched) ----------------
__global__ __launch_bounds__(256) void out_cvt_kernel(const float* __restrict__ outF, void* __restrict__ out,
                                                      const int* __restrict__ flag) {
    int i = blockIdx.x * 256 + threadIdx.x;
    if (i < NG * 64) {
        float v = outF[i];
        if (flag[0]) reinterpret_cast<u16*>(out)[i] = f2bf(v);
        else         reinterpret_cast<float*>(out)[i] = v;
    }
}

extern "C" void kernel_launch(void* const* d_in, const int* in_sizes, int n_in,
                              void* d_out, int out_size, void* d_ws, size_t ws_size,
                              hipStream_t stream) {
    const void* x     = d_in[0];
    const int* ei     = (const int*)d_in[1];
    const int* batch  = (const int*)d_in[2];
    const void* W_emb = d_in[3];
    const void* b_emb = d_in[4];
    const void* W1    = d_in[5];
    const void* b1    = d_in[6];
    const void* W2    = d_in[7];
    const void* b2    = d_in[8];
    const void* W3    = d_in[9];
    const void* b3    = d_in[10];

    char* p = (char*)d_ws;
    auto alloc = [&](size_t bytes) { void* r = p; p += (bytes + 255) & ~(size_t)255; return r; };
    int*   flag   = (int*)alloc(256);
    int*   counts = (int*)alloc(NN * 4);
    int*   cursor = (int*)alloc(NN * 4);
    int*   offs   = (int*)alloc(NN * 4);
    float* dis    = (float*)alloc(NN * 4);
    int*   bsums  = (int*)alloc(256 * 4);
    int*   srcs   = (int*)alloc((size_t)NE * 4);
    u16*   wembT  = (u16*)alloc(128 * 128 * 2);
    u16*   w1T    = (u16*)alloc(128 * 128 * 2);
    u16*   w2T    = (u16*)alloc(128 * 128 * 2);
    u16*   w3T    = (u16*)alloc(64 * 128 * 2);
    float* bembF  = (float*)alloc(128 * 4);
    float* b1F    = (float*)alloc(128 * 4);
    float* b2F    = (float*)alloc(128 * 4);
    float* b3F    = (float*)alloc(64 * 4);
    float* outF   = (float*)alloc((size_t)NG * 64 * 4);
    u16*   hA     = (u16*)alloc((size_t)(NN + 64) * 128 * 2);
    u16*   hB     = (u16*)alloc((size_t)(NN + 64) * 128 * 2);   // holds canonical bf16 x first

    hipMemsetAsync(counts, 0, NN * 4, stream);
    hipMemsetAsync(outF, 0, (size_t)NG * 64 * 4, stream);

    const int SB = (NN + 2047) / 2048;   // 49
    const int NB = (NN + 255) / 256;     // 391
    const int GB = (NN + 63) / 64;       // 1563

    detect_kernel<<<1, 256, 0, stream>>>((const u32*)x, flag);
    mega_prep<<<MEGA_NB, 256, 0, stream>>>(x, flag, hB, W_emb, W1, W2, W3, wembT, w1T, w2T, w3T,
                                           b_emb, b1, b2, b3, bembF, b1F, b2F, b3F, ei, counts);
    scan1_kernel<<<SB, 256, 0, stream>>>(counts, offs, bsums, dis, cursor);
    scan3_kernel<<<NB, 256, 0, stream>>>(offs, bsums);

    // gemm_emb (blocks [0,1563)) + scatter (blocks [1563,7813)) in one dispatch
    mega2_kernel<<<GB + (NE + 255) / 256, 256, 0, stream>>>(hB, (const u16*)x, flag, wembT, bembF, hA,
                                                            ei, offs, cursor, srcs);
    // layer-1 gemm: hA -> hB
    gemm_mfma128<<<GB, 256, 0, stream>>>(hA, w1T, hB);
    // fused agg1(+b1,relu) + gemm2: hB -> hA
    fused_agg_gemm<128><<<GB, 256, 0, stream>>>(hB, offs, counts, dis, srcs, b1F, w2T, hA);
    // fused agg2(+b2,relu) + gemm3: hA -> hB (64-wide out)
    fused_agg_gemm<64><<<GB, 256, 0, stream>>>(hA, offs, counts, dis, srcs, b2F, w3T, hB);
    // fused agg3(+b3) + pool: hB -> outF
    agg_pool_kernel<<<NN / 32, 256, 0, stream>>>(hB, offs, counts, dis, srcs, b3F, batch, outF);
    // outF -> d_out
    out_cvt_kernel<<<(NG * 64 + 255) / 256, 256, 0, stream>>>(outF, d_out, flag);
}